// Round 1
// 134.466 us; speedup vs baseline: 1.0344x; 1.0344x over previous
//
#include <hip/hip_runtime.h>

#define BLOCK 512
typedef float v2f __attribute__((ext_vector_type(2)));

// ---------- packed fp32 (VOP3P) ----------
__device__ __forceinline__ v2f pk_fma(v2f a, v2f b, v2f c) {
  v2f d;
  asm("v_pk_fma_f32 %0, %1, %2, %3" : "=v"(d) : "v"(a), "v"(b), "v"(c));
  return d;
}
__device__ __forceinline__ v2f pk_mul(v2f a, v2f b) {
  v2f d;
  asm("v_pk_mul_f32 %0, %1, %2" : "=v"(d) : "v"(a), "v"(b));
  return d;
}
// d = (s.lo * p.hi, s.hi * p.lo)  -- component-swapped src1 via op_sel
__device__ __forceinline__ v2f pk_mul_swap(v2f s, v2f p) {
  v2f d;
  asm("v_pk_mul_f32 %0, %1, %2 op_sel:[0,1] op_sel_hi:[1,0]" : "=v"(d) : "v"(s), "v"(p));
  return d;
}

// ---------- cross-lane xor within 16-lane rows (butterfly reduces) ----------
template<int CTRL>
__device__ __forceinline__ float dpp_f(float v) {
  return __int_as_float(__builtin_amdgcn_mov_dpp(__float_as_int(v), CTRL, 0xF, 0xF, true));
}
template<int MASK>
__device__ __forceinline__ float shx(float v) {
  if constexpr (MASK == 1)      return dpp_f<0xB1>(v);   // quad_perm xor1
  else if constexpr (MASK == 2) return dpp_f<0x4E>(v);   // quad_perm xor2
  else if constexpr (MASK == 8) return dpp_f<0x128>(v);  // row_ror:8 == xor8 in row16
  else  // MASK == 4: ds_swizzle BitMode xor=4
    return __int_as_float(__builtin_amdgcn_ds_swizzle(__float_as_int(v), 0x101F));
}

// forward one-layer index map in X basis: gates (0,1),(1,2),...,(6,7),(7,0),
// reversed-CNOT (c,t): bit c ^= bit t  (sequential, uses updated bits)
__device__ __forceinline__ int gmap(int b) {
#pragma unroll
  for (int j = 0; j < 7; ++j) b ^= ((b >> (j + 1)) & 1) << j;
  b ^= (b & 1) << 7;
  return b;
}

// dot of 8 v2f pair-products against one K2 column (stride 16 v2f between k's)
__device__ __forceinline__ float dotK(const v2f* pp, const v2f* kcol) {
  v2f a0; a0.x = 0.f; a0.y = 0.f;
  v2f a1; a1.x = 0.f; a1.y = 0.f;
#pragma unroll
  for (int k = 0; k < 8; k += 2) {
    a0 = pk_fma(pp[k],     kcol[k * 16],       a0);
    a1 = pk_fma(pp[k + 1], kcol[(k + 1) * 16], a1);
  }
  return (a0.x + a1.x) + (a0.y + a1.y);
}

// masks m_q = p^3(e_q): q0..q7 -> 0x32,0x56,0xAC,0x59,0xB3,0x66,0xCC,0x99
// (verified G^3(m_q) = e_q for the forward ring map G)
#define MQ_PACKED 0x99CC66B359AC5632ULL

__global__ __launch_bounds__(BLOCK, 4) void qcnn_kernel(
    const float* __restrict__ x,   const float* __restrict__ fcw,
    const float* __restrict__ fcb, const float* __restrict__ qp,
    const float* __restrict__ pw,  const float* __restrict__ pb,
    float* __restrict__ out)
{
  __shared__ float s_fcw[8 * 512];   // [q][e]
  __shared__ float s_pwt[8 * 512];   // transposed [q][o]
  __shared__ float s_pb[512];
  __shared__ float s_beta[256];      // total diagonal phase per X-basis index
  __shared__ v2f   s_K2[8][8][16];   // K[q][r2][u] = (K[q][u*16+2*r2], K[q][u*16+2*r2+1])

  const int tid = threadIdx.x;

  // ---- stage weights into LDS ----
#pragma unroll
  for (int i = tid; i < 1024; i += BLOCK)
    ((float4*)s_fcw)[i] = ((const float4*)fcw)[i];
#pragma unroll
  for (int i = tid; i < 4096; i += BLOCK)
    s_pwt[i] = pw[(i & 511) * 8 + (i >> 9)];
  if (tid < 128) ((float4*)s_pb)[tid] = ((const float4*)pb)[tid];

  // ---- beta[c]: phase angle of the collapsed diagonal D_tot ----
  // beta_c = A1(c) + A2(G(c)) + A3(G^2(c)),  A_l(i) = sum_q (i_q ? +1 : -1)*qp[l][q]/2
  if (tid < 256) {
    const int c = tid;
    const int i1 = gmap(c);
    const int i2 = gmap(i1);
    float ang = 0.f;
#pragma unroll
    for (int q = 0; q < 8; ++q) {
      ang += (((c  >> q) & 1) ? 0.5f : -0.5f) * qp[q];
      ang += (((i1 >> q) & 1) ? 0.5f : -0.5f) * qp[8 + q];
      ang += (((i2 >> q) & 1) ? 0.5f : -0.5f) * qp[16 + q];
    }
    s_beta[c] = ang;
  }
  __syncthreads();

  // ---- K tables: K_q[c] = cos(beta[c^m_q] - beta[c]) / 256 (norm folded in) ----
#pragma unroll
  for (int i = tid; i < 2048; i += BLOCK) {
    const int q = i >> 8, c = i & 255;
    const int m = (int)((MQ_PACKED >> (8 * q)) & 0xFF);
    const float kv = __cosf(s_beta[c ^ m] - s_beta[c]) * (1.0f / 256.0f);
    const int uu = c >> 4, rr = c & 15;
    ((float*)s_K2)[((q * 8 + (rr >> 1)) * 16 + uu) * 2 + (rr & 1)] = kv;
  }
  __syncthreads();

  const int wave = tid >> 6;
  const int lane = tid & 63;
  const int u = lane & 15;       // lane index within sample: circuit bits 4..7
  const int g = lane >> 4;       // sample group within wave

#pragma unroll 1
  for (int tile = 0; tile < 2; ++tile) {
    const int smp = blockIdx.x * 64 + tile * 32 + wave * 4 + g;

    // ---- Phase A: angles via packed dot products ----
    const float* xrow = x + (size_t)smp * 512;
    v2f acc2[8];
#pragma unroll
    for (int q = 0; q < 8; ++q) { acc2[q].x = 0.f; acc2[q].y = 0.f; }
#pragma unroll
    for (int t = 0; t < 8; ++t) {
      const float4 xv = *(const float4*)(xrow + u * 4 + t * 64);
      v2f x01; x01.x = xv.x; x01.y = xv.y;
      v2f x23; x23.x = xv.z; x23.y = xv.w;
#pragma unroll
      for (int q = 0; q < 8; ++q) {
        const float4 wv = *(const float4*)(s_fcw + q * 512 + u * 4 + t * 64);
        v2f w01; w01.x = wv.x; w01.y = wv.y;
        v2f w23; w23.x = wv.z; w23.y = wv.w;
        acc2[q] = pk_fma(x01, w01, acc2[q]);
        acc2[q] = pk_fma(x23, w23, acc2[q]);
      }
    }
    float th[8];
#pragma unroll
    for (int q = 0; q < 8; ++q) {
      float a_ = acc2[q].x + acc2[q].y;
      a_ += shx<1>(a_); a_ += shx<2>(a_); a_ += shx<4>(a_); a_ += shx<8>(a_);
      th[q] = a_ + fcb[q];
    }

    // ---- Phase B: X-basis product-state factors (real!) ----
    // per-qubit amps (unnormalized by sqrt2): bit0 -> u = c+s, bit1 -> v = c-s
    float uf[8], vf[8];
#pragma unroll
    for (int q = 0; q < 8; ++q) {
      const float h = 0.5f * th[q];
      const float c_ = __cosf(h), s_ = __sinf(h);
      uf[q] = c_ + s_; vf[q] = c_ - s_;
    }
    // reg-side products: wr2[k] = (wr[2k], wr[2k+1]) over circuit bits 0..3
    v2f wr2[8];
    {
      v2f P01; P01.x = uf[0]; P01.y = vf[0];
      const float r12[4] = {uf[1] * uf[2], vf[1] * uf[2], uf[1] * vf[2], vf[1] * vf[2]};
#pragma unroll
      for (int k = 0; k < 8; ++k) {
        const float rest = r12[k & 3] * ((k & 4) ? vf[3] : uf[3]);
        v2f rr; rr.x = rest; rr.y = rest;
        wr2[k] = pk_mul(P01, rr);
      }
    }
    // lane-side factor pairs: wup[q] = wu(u) * wu(u ^ mL_q), computed arithmetically
    float wup[8];
    {
      const bool b4 = (u & 1), b5 = (u & 2), b6 = (u & 4), b7 = (u & 8);
      const float f4 = b4 ? vf[4] : uf[4], g4 = b4 ? uf[4] : vf[4];
      const float f5 = b5 ? vf[5] : uf[5], g5 = b5 ? uf[5] : vf[5];
      const float f6 = b6 ? vf[6] : uf[6], g6 = b6 ? uf[6] : vf[6];
      const float f7 = b7 ? vf[7] : uf[7], g7 = b7 ? uf[7] : vf[7];
      const float A0 = f4 * f5, A1 = g4 * f5, A2 = f4 * g5, A3 = g4 * g5;
      const float B0 = f6 * f7, B1 = g6 * f7, B2 = f6 * g7, B3 = g6 * g7;
      const float wu = A0 * B0;
      wup[0] = wu * (A3 * B0);   // mL=3  flips {4,5}
      wup[1] = wu * (A1 * B1);   // mL=5  flips {4,6}
      wup[2] = wu * (A2 * B2);   // mL=A  flips {5,7}
      wup[3] = wup[1];           // mL=5  flips {4,6}
      wup[4] = wu * (A3 * B2);   // mL=B  flips {4,5,7}
      wup[5] = wu * (A2 * B1);   // mL=6  flips {5,6}
      wup[6] = wu * (A0 * B3);   // mL=C  flips {6,7}
      wup[7] = wu * (A1 * B2);   // mL=9  flips {4,7}
    }

    // ---- Phase C': z_q = sum_c w_c * w_{c^m_q} * K_q[c] ----
    // reg parts mR = {2,6,C,9,3,6,C,9}: 5 distinct pair-product patterns
    float zp[8];
    {
      const v2f* kb = (const v2f*)s_K2 + u;
      v2f pp[8];
      // q0: mR=2 (even) -> partner wr2[k^1]
#pragma unroll
      for (int k = 0; k < 8; ++k) pp[k] = pk_mul(wr2[k], wr2[k ^ 1]);
      zp[0] = dotK(pp, kb + 0 * 128) * wup[0];
      // q4: mR=3 (odd) -> swapped partner wr2[k^1]
#pragma unroll
      for (int k = 0; k < 8; ++k) pp[k] = pk_mul_swap(wr2[k], wr2[k ^ 1]);
      zp[4] = dotK(pp, kb + 4 * 128) * wup[4];
      // q1,q5: mR=6 (even) -> wr2[k^3]
#pragma unroll
      for (int k = 0; k < 8; ++k) pp[k] = pk_mul(wr2[k], wr2[k ^ 3]);
      zp[1] = dotK(pp, kb + 1 * 128) * wup[1];
      zp[5] = dotK(pp, kb + 5 * 128) * wup[5];
      // q2,q6: mR=C (even) -> wr2[k^6]
#pragma unroll
      for (int k = 0; k < 8; ++k) pp[k] = pk_mul(wr2[k], wr2[k ^ 6]);
      zp[2] = dotK(pp, kb + 2 * 128) * wup[2];
      zp[6] = dotK(pp, kb + 6 * 128) * wup[6];
      // q3,q7: mR=9 (odd) -> swapped partner wr2[k^4]
#pragma unroll
      for (int k = 0; k < 8; ++k) pp[k] = pk_mul_swap(wr2[k], wr2[k ^ 4]);
      zp[3] = dotK(pp, kb + 3 * 128) * wup[3];
      zp[7] = dotK(pp, kb + 7 * 128) * wup[7];
    }
    // sum over the 16 lanes of the sample (result broadcast to all lanes)
#pragma unroll
    for (int q = 0; q < 8; ++q) zp[q] += shx<1>(zp[q]);
#pragma unroll
    for (int q = 0; q < 8; ++q) zp[q] += shx<2>(zp[q]);
#pragma unroll
    for (int q = 0; q < 8; ++q) zp[q] += shx<4>(zp[q]);
#pragma unroll
    for (int q = 0; q < 8; ++q) zp[q] += shx<8>(zp[q]);

    // ---- Phase E: out = z @ post_w^T + post_b (packed) ----
    v2f zz[8];
#pragma unroll
    for (int q = 0; q < 8; ++q) { zz[q].x = zp[q]; zz[q].y = zp[q]; }
    float* orow = out + (size_t)smp * 512;
#pragma unroll
    for (int tt = 0; tt < 8; ++tt) {
      const int o = u * 4 + tt * 64;
      const float4 pbv = *(const float4*)(s_pb + o);
      v2f r0; r0.x = pbv.x; r0.y = pbv.y;
      v2f r1; r1.x = pbv.z; r1.y = pbv.w;
#pragma unroll
      for (int q = 0; q < 8; ++q) {
        const float4 wv = *(const float4*)(s_pwt + q * 512 + o);
        v2f w01; w01.x = wv.x; w01.y = wv.y;
        v2f w23; w23.x = wv.z; w23.y = wv.w;
        r0 = pk_fma(zz[q], w01, r0);
        r1 = pk_fma(zz[q], w23, r1);
      }
      float4 ov; ov.x = r0.x; ov.y = r0.y; ov.z = r1.x; ov.w = r1.y;
      *(float4*)(orow + o) = ov;
    }
  }
}

extern "C" void kernel_launch(void* const* d_in, const int* in_sizes, int n_in,
                              void* d_out, int out_size, void* d_ws, size_t ws_size,
                              hipStream_t stream) {
  const float* x   = (const float*)d_in[0];
  const float* fcw = (const float*)d_in[1];
  const float* fcb = (const float*)d_in[2];
  const float* qp  = (const float*)d_in[3];
  const float* pw  = (const float*)d_in[4];
  const float* pb  = (const float*)d_in[5];
  float* out = (float*)d_out;

  // 32768 samples / (4 per wave * 8 waves * 2 tiles per block) = 512 blocks
  dim3 grid(512), block(BLOCK);
  hipLaunchKernelGGL(qcnn_kernel, grid, block, 0, stream, x, fcw, fcb, qp, pw, pb, out);
}

// Round 2
// 124.589 us; speedup vs baseline: 1.1165x; 1.0793x over previous
//
#include <hip/hip_runtime.h>

#define BLOCK 512
typedef float v2f __attribute__((ext_vector_type(2)));

// ---------- packed fp32 (VOP3P) ----------
__device__ __forceinline__ v2f pk_fma(v2f a, v2f b, v2f c) {
  v2f d;
  asm("v_pk_fma_f32 %0, %1, %2, %3" : "=v"(d) : "v"(a), "v"(b), "v"(c));
  return d;
}
__device__ __forceinline__ v2f pk_mul(v2f a, v2f b) {
  v2f d;
  asm("v_pk_mul_f32 %0, %1, %2" : "=v"(d) : "v"(a), "v"(b));
  return d;
}
// d = (s.lo * p.hi, s.hi * p.lo)  -- component-swapped src1 via op_sel
__device__ __forceinline__ v2f pk_mul_swap(v2f s, v2f p) {
  v2f d;
  asm("v_pk_mul_f32 %0, %1, %2 op_sel:[0,1] op_sel_hi:[1,0]" : "=v"(d) : "v"(s), "v"(p));
  return d;
}

// ---------- cross-lane xor within 16-lane rows (butterfly reduces) ----------
template<int CTRL>
__device__ __forceinline__ float dpp_f(float v) {
  return __int_as_float(__builtin_amdgcn_mov_dpp(__float_as_int(v), CTRL, 0xF, 0xF, true));
}
template<int MASK>
__device__ __forceinline__ float shx(float v) {
  if constexpr (MASK == 1)      return dpp_f<0xB1>(v);   // quad_perm xor1
  else if constexpr (MASK == 2) return dpp_f<0x4E>(v);   // quad_perm xor2
  else if constexpr (MASK == 8) return dpp_f<0x128>(v);  // row_ror:8 == xor8 in row16
  else  // MASK == 4: ds_swizzle BitMode xor=4
    return __int_as_float(__builtin_amdgcn_ds_swizzle(__float_as_int(v), 0x101F));
}

// forward one-layer index map in X basis: gates (0,1),(1,2),...,(6,7),(7,0),
// reversed-CNOT (c,t): bit c ^= bit t  (sequential, uses updated bits)
__device__ __forceinline__ int gmap(int b) {
#pragma unroll
  for (int j = 0; j < 7; ++j) b ^= ((b >> (j + 1)) & 1) << j;
  b ^= (b & 1) << 7;
  return b;
}

// masks m_q = p^3(e_q): q0..q7 -> 0x32,0x56,0xAC,0x59,0xB3,0x66,0xCC,0x99
#define MQ_PACKED 0x99CC66B359AC5632ULL

// build X-basis product-state pieces for one sample row
// wr2[k] = (w[2k], w[2k+1]) over circuit bits 0..3; wup[q] = wu(u)*wu(u^mL_q)
__device__ __forceinline__ void build_w(const float* th, int u, v2f* wr2, float* wup) {
  float uf[8], vf[8];
#pragma unroll
  for (int q = 0; q < 8; ++q) {
    const float h = 0.5f * th[q];
    const float c_ = __cosf(h), s_ = __sinf(h);
    uf[q] = c_ + s_; vf[q] = c_ - s_;
  }
  v2f P01; P01.x = uf[0]; P01.y = vf[0];
  const float r12[4] = {uf[1] * uf[2], vf[1] * uf[2], uf[1] * vf[2], vf[1] * vf[2]};
#pragma unroll
  for (int k = 0; k < 8; ++k) {
    const float rest = r12[k & 3] * ((k & 4) ? vf[3] : uf[3]);
    v2f rr; rr.x = rest; rr.y = rest;
    wr2[k] = pk_mul(P01, rr);
  }
  const bool b4 = (u & 1), b5 = (u & 2), b6 = (u & 4), b7 = (u & 8);
  const float f4 = b4 ? vf[4] : uf[4], g4 = b4 ? uf[4] : vf[4];
  const float f5 = b5 ? vf[5] : uf[5], g5 = b5 ? uf[5] : vf[5];
  const float f6 = b6 ? vf[6] : uf[6], g6 = b6 ? uf[6] : vf[6];
  const float f7 = b7 ? vf[7] : uf[7], g7 = b7 ? uf[7] : vf[7];
  const float A0 = f4 * f5, A1 = g4 * f5, A2 = f4 * g5, A3 = g4 * g5;
  const float B0 = f6 * f7, B1 = g6 * f7, B2 = f6 * g7, B3 = g6 * g7;
  const float wu = A0 * B0;
  wup[0] = wu * (A3 * B0);   // mL=3  flips {4,5}
  wup[1] = wu * (A1 * B1);   // mL=5  flips {4,6}
  wup[2] = wu * (A2 * B2);   // mL=A  flips {5,7}
  wup[3] = wup[1];           // mL=5  flips {4,6}
  wup[4] = wu * (A3 * B2);   // mL=B  flips {4,5,7}
  wup[5] = wu * (A2 * B1);   // mL=6  flips {5,6}
  wup[6] = wu * (A0 * B3);   // mL=C  flips {6,7}
  wup[7] = wu * (A1 * B2);   // mL=9  flips {4,7}
}

__global__ __launch_bounds__(BLOCK, 4) void qcnn_kernel(
    const float* __restrict__ x,   const float* __restrict__ fcw,
    const float* __restrict__ fcb, const float* __restrict__ qp,
    const float* __restrict__ pw,  const float* __restrict__ pb,
    float* __restrict__ out)
{
  __shared__ float s_fcw[8 * 512];   // [q][e]
  __shared__ float s_pwt[8 * 512];   // transposed [q][o]
  __shared__ float s_pb[512];
  __shared__ float s_beta[256];      // total diagonal phase per X-basis index
  __shared__ v2f   s_K2[8][8][16];   // K[q][r2][u]

  const int tid = threadIdx.x;

  // ---- stage weights into LDS ----
#pragma unroll
  for (int i = tid; i < 1024; i += BLOCK)
    ((float4*)s_fcw)[i] = ((const float4*)fcw)[i];
#pragma unroll
  for (int i = tid; i < 4096; i += BLOCK)
    s_pwt[i] = pw[(i & 511) * 8 + (i >> 9)];
  if (tid < 128) ((float4*)s_pb)[tid] = ((const float4*)pb)[tid];

  // ---- beta[c]: phase angle of the collapsed diagonal D_tot ----
  if (tid < 256) {
    const int c = tid;
    const int i1 = gmap(c);
    const int i2 = gmap(i1);
    float ang = 0.f;
#pragma unroll
    for (int q = 0; q < 8; ++q) {
      ang += (((c  >> q) & 1) ? 0.5f : -0.5f) * qp[q];
      ang += (((i1 >> q) & 1) ? 0.5f : -0.5f) * qp[8 + q];
      ang += (((i2 >> q) & 1) ? 0.5f : -0.5f) * qp[16 + q];
    }
    s_beta[c] = ang;
  }
  __syncthreads();

  // ---- K tables: K_q[c] = cos(beta[c^m_q] - beta[c]) / 256 ----
#pragma unroll
  for (int i = tid; i < 2048; i += BLOCK) {
    const int q = i >> 8, c = i & 255;
    const int m = (int)((MQ_PACKED >> (8 * q)) & 0xFF);
    const float kv = __cosf(s_beta[c ^ m] - s_beta[c]) * (1.0f / 256.0f);
    const int uu = c >> 4, rr = c & 15;
    ((float*)s_K2)[((q * 8 + (rr >> 1)) * 16 + uu) * 2 + (rr & 1)] = kv;
  }
  __syncthreads();

  const int wave = tid >> 6;
  const int lane = tid & 63;
  const int u = lane & 15;       // lane index within sample: circuit bits 4..7
  const int g = lane >> 4;       // sample group within wave

  // 8 samples per wave: 2 rows per lane-group, sharing every LDS read
  const int base = blockIdx.x * 64 + wave * 8;
  const int sA = base + g;
  const int sB = base + 4 + g;

  // ---- Phase A: angles via packed dot products, 2 rows per lane ----
  const float* xrA = x + (size_t)sA * 512;
  const float* xrB = x + (size_t)sB * 512;
  v2f accA[8], accB[8];
#pragma unroll
  for (int q = 0; q < 8; ++q) {
    accA[q].x = 0.f; accA[q].y = 0.f;
    accB[q].x = 0.f; accB[q].y = 0.f;
  }
#pragma unroll
  for (int t = 0; t < 8; ++t) {
    const float4 xa = *(const float4*)(xrA + u * 4 + t * 64);
    const float4 xb = *(const float4*)(xrB + u * 4 + t * 64);
    v2f xa01; xa01.x = xa.x; xa01.y = xa.y;
    v2f xa23; xa23.x = xa.z; xa23.y = xa.w;
    v2f xb01; xb01.x = xb.x; xb01.y = xb.y;
    v2f xb23; xb23.x = xb.z; xb23.y = xb.w;
#pragma unroll
    for (int q = 0; q < 8; ++q) {
      const float4 wv = *(const float4*)(s_fcw + q * 512 + u * 4 + t * 64);
      v2f w01; w01.x = wv.x; w01.y = wv.y;
      v2f w23; w23.x = wv.z; w23.y = wv.w;
      accA[q] = pk_fma(xa01, w01, accA[q]);
      accA[q] = pk_fma(xa23, w23, accA[q]);
      accB[q] = pk_fma(xb01, w01, accB[q]);
      accB[q] = pk_fma(xb23, w23, accB[q]);
    }
  }
  float thA[8], thB[8];
#pragma unroll
  for (int q = 0; q < 8; ++q) {
    float aA = accA[q].x + accA[q].y;
    float aB = accB[q].x + accB[q].y;
    aA += shx<1>(aA); aB += shx<1>(aB);
    aA += shx<2>(aA); aB += shx<2>(aB);
    aA += shx<4>(aA); aB += shx<4>(aB);
    aA += shx<8>(aA); aB += shx<8>(aB);
    const float fb = fcb[q];
    thA[q] = aA + fb; thB[q] = aB + fb;
  }

  // ---- Phase B: X-basis real product-state factors, both rows ----
  v2f wA[8], wB[8];
  float wupA[8], wupB[8];
  build_w(thA, u, wA, wupA);
  build_w(thB, u, wB, wupB);

  // ---- Phase C: z_q = sum_c w_c * w_{c^m_q} * K_q[c]; K reads shared by rows ----
  float zpA[8], zpB[8];
  {
    const v2f* kb = (const v2f*)s_K2 + u;
    // q0: mR=2 (even) -> partner wr2[k^1]
    {
      v2f aA; aA.x = 0.f; aA.y = 0.f; v2f aB = aA;
#pragma unroll
      for (int k = 0; k < 8; ++k) {
        const v2f kv = kb[0 * 128 + k * 16];
        aA = pk_fma(pk_mul(wA[k], wA[k ^ 1]), kv, aA);
        aB = pk_fma(pk_mul(wB[k], wB[k ^ 1]), kv, aB);
      }
      zpA[0] = (aA.x + aA.y) * wupA[0];
      zpB[0] = (aB.x + aB.y) * wupB[0];
    }
    // q4: mR=3 (odd) -> swapped partner wr2[k^1]
    {
      v2f aA; aA.x = 0.f; aA.y = 0.f; v2f aB = aA;
#pragma unroll
      for (int k = 0; k < 8; ++k) {
        const v2f kv = kb[4 * 128 + k * 16];
        aA = pk_fma(pk_mul_swap(wA[k], wA[k ^ 1]), kv, aA);
        aB = pk_fma(pk_mul_swap(wB[k], wB[k ^ 1]), kv, aB);
      }
      zpA[4] = (aA.x + aA.y) * wupA[4];
      zpB[4] = (aB.x + aB.y) * wupB[4];
    }
    // q1,q5: mR=6 (even) -> wr2[k^3], two K columns share the pair-products
    {
      v2f a1A, a5A, a1B, a5B;
      a1A.x = a1A.y = a5A.x = a5A.y = 0.f;
      a1B.x = a1B.y = a5B.x = a5B.y = 0.f;
#pragma unroll
      for (int k = 0; k < 8; ++k) {
        const v2f k1 = kb[1 * 128 + k * 16];
        const v2f k5 = kb[5 * 128 + k * 16];
        const v2f pA = pk_mul(wA[k], wA[k ^ 3]);
        const v2f pB = pk_mul(wB[k], wB[k ^ 3]);
        a1A = pk_fma(pA, k1, a1A); a5A = pk_fma(pA, k5, a5A);
        a1B = pk_fma(pB, k1, a1B); a5B = pk_fma(pB, k5, a5B);
      }
      zpA[1] = (a1A.x + a1A.y) * wupA[1]; zpA[5] = (a5A.x + a5A.y) * wupA[5];
      zpB[1] = (a1B.x + a1B.y) * wupB[1]; zpB[5] = (a5B.x + a5B.y) * wupB[5];
    }
    // q2,q6: mR=C (even) -> wr2[k^6]
    {
      v2f a2A, a6A, a2B, a6B;
      a2A.x = a2A.y = a6A.x = a6A.y = 0.f;
      a2B.x = a2B.y = a6B.x = a6B.y = 0.f;
#pragma unroll
      for (int k = 0; k < 8; ++k) {
        const v2f k2 = kb[2 * 128 + k * 16];
        const v2f k6 = kb[6 * 128 + k * 16];
        const v2f pA = pk_mul(wA[k], wA[k ^ 6]);
        const v2f pB = pk_mul(wB[k], wB[k ^ 6]);
        a2A = pk_fma(pA, k2, a2A); a6A = pk_fma(pA, k6, a6A);
        a2B = pk_fma(pB, k2, a2B); a6B = pk_fma(pB, k6, a6B);
      }
      zpA[2] = (a2A.x + a2A.y) * wupA[2]; zpA[6] = (a6A.x + a6A.y) * wupA[6];
      zpB[2] = (a2B.x + a2B.y) * wupB[2]; zpB[6] = (a6B.x + a6B.y) * wupB[6];
    }
    // q3,q7: mR=9 (odd) -> swapped partner wr2[k^4]
    {
      v2f a3A, a7A, a3B, a7B;
      a3A.x = a3A.y = a7A.x = a7A.y = 0.f;
      a3B.x = a3B.y = a7B.x = a7B.y = 0.f;
#pragma unroll
      for (int k = 0; k < 8; ++k) {
        const v2f k3 = kb[3 * 128 + k * 16];
        const v2f k7 = kb[7 * 128 + k * 16];
        const v2f pA = pk_mul_swap(wA[k], wA[k ^ 4]);
        const v2f pB = pk_mul_swap(wB[k], wB[k ^ 4]);
        a3A = pk_fma(pA, k3, a3A); a7A = pk_fma(pA, k7, a7A);
        a3B = pk_fma(pB, k3, a3B); a7B = pk_fma(pB, k7, a7B);
      }
      zpA[3] = (a3A.x + a3A.y) * wupA[3]; zpA[7] = (a7A.x + a7A.y) * wupA[7];
      zpB[3] = (a3B.x + a3B.y) * wupB[3]; zpB[7] = (a7B.x + a7B.y) * wupB[7];
    }
  }
  // sum over the 16 lanes of the sample (result broadcast to all lanes)
#pragma unroll
  for (int q = 0; q < 8; ++q) { zpA[q] += shx<1>(zpA[q]); zpB[q] += shx<1>(zpB[q]); }
#pragma unroll
  for (int q = 0; q < 8; ++q) { zpA[q] += shx<2>(zpA[q]); zpB[q] += shx<2>(zpB[q]); }
#pragma unroll
  for (int q = 0; q < 8; ++q) { zpA[q] += shx<4>(zpA[q]); zpB[q] += shx<4>(zpB[q]); }
#pragma unroll
  for (int q = 0; q < 8; ++q) { zpA[q] += shx<8>(zpA[q]); zpB[q] += shx<8>(zpB[q]); }

  // ---- Phase E: out = z @ post_w^T + post_b, 2 rows share weight reads ----
  v2f zzA[8], zzB[8];
#pragma unroll
  for (int q = 0; q < 8; ++q) {
    zzA[q].x = zpA[q]; zzA[q].y = zpA[q];
    zzB[q].x = zpB[q]; zzB[q].y = zpB[q];
  }
  float* orA = out + (size_t)sA * 512;
  float* orB = out + (size_t)sB * 512;
#pragma unroll
  for (int tt = 0; tt < 8; ++tt) {
    const int o = u * 4 + tt * 64;
    const float4 pbv = *(const float4*)(s_pb + o);
    v2f rA0; rA0.x = pbv.x; rA0.y = pbv.y;
    v2f rA1; rA1.x = pbv.z; rA1.y = pbv.w;
    v2f rB0 = rA0, rB1 = rA1;
#pragma unroll
    for (int q = 0; q < 8; ++q) {
      const float4 wv = *(const float4*)(s_pwt + q * 512 + o);
      v2f w01; w01.x = wv.x; w01.y = wv.y;
      v2f w23; w23.x = wv.z; w23.y = wv.w;
      rA0 = pk_fma(zzA[q], w01, rA0);
      rA1 = pk_fma(zzA[q], w23, rA1);
      rB0 = pk_fma(zzB[q], w01, rB0);
      rB1 = pk_fma(zzB[q], w23, rB1);
    }
    float4 ovA; ovA.x = rA0.x; ovA.y = rA0.y; ovA.z = rA1.x; ovA.w = rA1.y;
    float4 ovB; ovB.x = rB0.x; ovB.y = rB0.y; ovB.z = rB1.x; ovB.w = rB1.y;
    *(float4*)(orA + o) = ovA;
    *(float4*)(orB + o) = ovB;
  }
}

extern "C" void kernel_launch(void* const* d_in, const int* in_sizes, int n_in,
                              void* d_out, int out_size, void* d_ws, size_t ws_size,
                              hipStream_t stream) {
  const float* x   = (const float*)d_in[0];
  const float* fcw = (const float*)d_in[1];
  const float* fcb = (const float*)d_in[2];
  const float* qp  = (const float*)d_in[3];
  const float* pw  = (const float*)d_in[4];
  const float* pb  = (const float*)d_in[5];
  float* out = (float*)d_out;

  // 32768 samples / (8 per wave * 8 waves per block) = 512 blocks
  dim3 grid(512), block(BLOCK);
  hipLaunchKernelGGL(qcnn_kernel, grid, block, 0, stream, x, fcw, fcb, qp, pw, pb, out);
}